// Round 1
// 969.532 us; speedup vs baseline: 1.3662x; 1.3662x over previous
//
#include <hip/hip_runtime.h>

#define NUM_USERS 200000
#define NUM_ITEMS 100000
#define NN (NUM_USERS + NUM_ITEMS)   // 300000
#define D 32
#define NE 9600000
#define TOTAL (NN * D)               // 9,600,000 floats

#define RPB2 128                     // rows per fine bucket
#define B2 ((NN + RPB2 - 1) / RPB2)  // 2344 buckets; region == CSR slice of 128 rows
#define CAP 5120                     // LDS stage capacity (mean 4096, sigma ~64)

#define TPB_A 1024                   // partition block size
#define EPT 16                       // edges per thread in partition
#define EPB_A (TPB_A * EPT)          // 16384 edges per block

#define TPB_H 1024                   // bucket-hist block size
#define EPT_H 32                     // edges per thread in bucket-hist
#define EPB_H (TPB_H * EPT_H)        // 32768 edges per block
#define NB_H ((NE + EPB_H - 1) / EPB_H)  // 293 blocks

// ---------------------------------------------------------------------------
// init: x0 = concat(user_w, item_w); acc = x0. Runs AFTER the CSR build
// because the build's temp array aliases the x|y workspace.
__global__ __launch_bounds__(256) void init_x_acc(
    const float4* __restrict__ user_w, const float4* __restrict__ item_w,
    float4* __restrict__ x, float4* __restrict__ acc) {
    int i = blockIdx.x * 256 + threadIdx.x;
    const int total4 = TOTAL / 4;
    const int ub4 = (NUM_USERS * D) / 4;
    if (i < total4) {
        float4 v = (i < ub4) ? user_w[i] : item_w[i - ub4];
        x[i] = v;
        acc[i] = v;
    }
}

// ---------------------------------------------------------------------------
// Bucket-granular degree histogram, LDS-privatized. Replaces the old per-row
// hist_kernel whose 9.6M device-scope atomics generated ~300MB of HBM
// write-through (372 us). Here: 9.6M LDS atomics + ~0.7M global atomics.
__global__ __launch_bounds__(TPB_H) void bucket_hist(
    const int4* __restrict__ rows4, int* __restrict__ bcounts) {
    __shared__ int hist[B2];                         // 9376 B
    int tid = threadIdx.x;
    for (int i = tid; i < B2; i += TPB_H) hist[i] = 0;
    __syncthreads();
    int base4 = blockIdx.x * (EPB_H / 4);
    #pragma unroll
    for (int k = 0; k < EPT_H / 4; ++k) {
        int i4 = base4 + k * TPB_H + tid;
        if (i4 < NE / 4) {
            int4 r = rows4[i4];
            atomicAdd(&hist[r.x >> 7], 1);
            atomicAdd(&hist[r.y >> 7], 1);
            atomicAdd(&hist[r.z >> 7], 1);
            atomicAdd(&hist[r.w >> 7], 1);
        }
    }
    __syncthreads();
    for (int b = tid; b < B2; b += TPB_H) {
        int c = hist[b];
        if (c) atomicAdd(&bcounts[b], c);
    }
}

// ---------------------------------------------------------------------------
// Single-block exclusive scan of the 2344 bucket counts. Each thread owns 4
// consecutive buckets; Hillis-Steele over the 1024 partial sums. Writes both
// bstart (persistent, read by sort_bucket2) and bfill (consumed by
// partition_edges as its run-reservation counters). Replaces the old 3-pass
// 300K-element scan + bucket_starts.
__global__ __launch_bounds__(1024) void scan_buckets(
    const int* __restrict__ bcounts, int* __restrict__ bstart,
    int* __restrict__ bfill) {
    __shared__ int lds[1024];
    int t = threadIdx.x;
    int v[4];
    int s = 0;
    #pragma unroll
    for (int k = 0; k < 4; ++k) {
        int b = t * 4 + k;
        v[k] = (b < B2) ? bcounts[b] : 0;
        s += v[k];
    }
    lds[t] = s;
    __syncthreads();
    for (int off = 1; off < 1024; off <<= 1) {
        int u = (t >= off) ? lds[t - off] : 0;
        __syncthreads();
        lds[t] += u;
        __syncthreads();
    }
    int ex = lds[t] - s;                             // exclusive prefix of chunk
    #pragma unroll
    for (int k = 0; k < 4; ++k) {
        int b = t * 4 + k;
        if (b < B2) { bstart[b] = ex; bfill[b] = ex; }
        ex += v[k];
    }
    if (t == 1023) bstart[B2] = ex;                  // == NE
}

// ---------------------------------------------------------------------------
// Pass A: block-privatized counting-split of edges into the 2344 bucket
// regions of temp. Per block: LDS histogram -> per-edge rank; one global
// atomicAdd per touched bucket reserves a contiguous run; phase-2 reload
// writes (row_local<<19|col, val) at base+rank — dense ~56B runs per CU.
__global__ __launch_bounds__(TPB_A) void partition_edges(
    const int4* __restrict__ rows4, const int4* __restrict__ cols4,
    const float4* __restrict__ vals4, int* __restrict__ bfill,
    int2* __restrict__ temp) {
    __shared__ int hist[B2];                         // 9376 B
    int tid = threadIdx.x;
    for (int i = tid; i < B2; i += TPB_A) hist[i] = 0;
    __syncthreads();

    int base4 = blockIdx.x * (EPB_A / 4);
    int brank[EPT];                                  // (bucket<<16)|rank per edge

    #pragma unroll
    for (int k = 0; k < EPT / 4; ++k) {
        int i4 = base4 + k * TPB_A + tid;
        if (i4 < NE / 4) {
            int4 r = rows4[i4];
            int b0 = r.x >> 7, b1 = r.y >> 7, b2 = r.z >> 7, b3 = r.w >> 7;
            brank[k * 4 + 0] = (b0 << 16) | atomicAdd(&hist[b0], 1);
            brank[k * 4 + 1] = (b1 << 16) | atomicAdd(&hist[b1], 1);
            brank[k * 4 + 2] = (b2 << 16) | atomicAdd(&hist[b2], 1);
            brank[k * 4 + 3] = (b3 << 16) | atomicAdd(&hist[b3], 1);
        }
    }
    __syncthreads();
    for (int b = tid; b < B2; b += TPB_A) {          // reserve runs
        int c = hist[b];
        if (c) hist[b] = atomicAdd(&bfill[b], c);    // hist now holds base
    }
    __syncthreads();

    #pragma unroll
    for (int k = 0; k < EPT / 4; ++k) {
        int i4 = base4 + k * TPB_A + tid;
        if (i4 < NE / 4) {
            int4 r = rows4[i4];
            int4 c = cols4[i4];
            float4 v = vals4[i4];
            int br, pos; int2 cv;
            br = brank[k * 4 + 0]; pos = hist[br >> 16] + (br & 0xFFFF);
            cv.x = ((r.x & 127) << 19) | c.x; cv.y = __float_as_int(v.x); temp[pos] = cv;
            br = brank[k * 4 + 1]; pos = hist[br >> 16] + (br & 0xFFFF);
            cv.x = ((r.y & 127) << 19) | c.y; cv.y = __float_as_int(v.y); temp[pos] = cv;
            br = brank[k * 4 + 2]; pos = hist[br >> 16] + (br & 0xFFFF);
            cv.x = ((r.z & 127) << 19) | c.z; cv.y = __float_as_int(v.z); temp[pos] = cv;
            br = brank[k * 4 + 3]; pos = hist[br >> 16] + (br & 0xFFFF);
            cv.x = ((r.w & 127) << 19) | c.w; cv.y = __float_as_int(v.w); temp[pos] = cv;
        }
    }
}

// ---------------------------------------------------------------------------
// Pass B: exact within-bucket counting sort through LDS, now also producing
// row_start. One block per bucket: pass 1 counts the 128 row-locals (LDS
// atomics) from a sequential read of the temp region; 128-wide LDS scan
// yields the per-row exclusive offsets, which are emitted as row_start;
// pass 2 re-reads the region, ranks, stages (col,val) in LDS, and flushes
// fully coalesced. Fallback (count > CAP, never for uniform data) scatters
// directly to colval using the same LDS offsets — no global gfill needed.
__global__ __launch_bounds__(256) void sort_bucket2(
    const int* __restrict__ bstart, const int2* __restrict__ temp,
    int* __restrict__ row_start, int2* __restrict__ colval) {
    __shared__ int2 stage[CAP];                      // 40 KB
    __shared__ int lstart[RPB2];
    __shared__ int lfill[RPB2];
    int b = blockIdx.x;
    int row0 = b * RPB2;
    int rcount = NN - row0; if (rcount > RPB2) rcount = RPB2;
    int tid = threadIdx.x;
    int s = bstart[b];
    int count = bstart[b + 1] - s;

    if (tid < RPB2) lfill[tid] = 0;
    __syncthreads();

    // pass 1: per-row counts of this bucket's edges
    for (int i = tid; i < count; i += 256) {
        int rl = temp[s + i].x >> 19;
        atomicAdd(&lfill[rl], 1);
    }
    __syncthreads();

    // 128-wide Hillis-Steele scan -> exclusive per-row offsets
    int val = (tid < RPB2) ? lfill[tid] : 0;
    if (tid < RPB2) lstart[tid] = val;
    __syncthreads();
    for (int off = 1; off < RPB2; off <<= 1) {
        int u = (tid >= off && tid < RPB2) ? lstart[tid - off] : 0;
        __syncthreads();
        if (tid < RPB2) lstart[tid] += u;
        __syncthreads();
    }
    int ex = (tid < RPB2) ? lstart[tid] - val : 0;
    if (tid < RPB2) {
        lstart[tid] = ex;
        lfill[tid] = 0;                              // reset for rank pass
        if (tid < rcount) row_start[row0 + tid] = s + ex;
    }
    if (b == 0 && tid == 0) row_start[NN] = NE;
    __syncthreads();

    // pass 2: rank + stage + coalesced flush
    if (count <= CAP) {
        for (int i = tid; i < count; i += 256) {
            int2 e = temp[s + i];
            int rl = e.x >> 19;
            int pos = lstart[rl] + atomicAdd(&lfill[rl], 1);
            stage[pos] = make_int2(e.x & 0x7FFFF, e.y);
        }
        __syncthreads();
        for (int i = tid; i < count; i += 256) colval[s + i] = stage[i];
    } else {
        for (int i = tid; i < count; i += 256) {
            int2 e = temp[s + i];
            int rl = e.x >> 19;
            int pos = lstart[rl] + atomicAdd(&lfill[rl], 1);
            colval[s + pos] = make_int2(e.x & 0x7FFFF, e.y);
        }
    }
}

// ---------------------------------------------------------------------------
// Atomic-free SpMM: one 32-lane half-wave per row (lane = feature d).
// Unroll-8: 8 independent 128B gathers in flight per half-wave.
// Fused y store + acc += y (and *0.25 on the last layer).
template <bool LAST>
__global__ __launch_bounds__(256) void spmm_csr(
    const int* __restrict__ row_start, const int2* __restrict__ colval,
    const float* __restrict__ x, float* __restrict__ y,
    float* __restrict__ acc) {
    int lane = threadIdx.x & 31;
    int row = blockIdx.x * 8 + (threadIdx.x >> 5);
    if (row >= NN) return;
    int s = row_start[row];
    int e = row_start[row + 1];
    float s0 = 0.f, s1 = 0.f, s2 = 0.f, s3 = 0.f;
    float s4 = 0.f, s5 = 0.f, s6 = 0.f, s7 = 0.f;
    int i = s;
    for (; i + 7 < e; i += 8) {
        int2 a0 = colval[i];
        int2 a1 = colval[i + 1];
        int2 a2 = colval[i + 2];
        int2 a3 = colval[i + 3];
        int2 a4 = colval[i + 4];
        int2 a5 = colval[i + 5];
        int2 a6 = colval[i + 6];
        int2 a7 = colval[i + 7];
        s0 += __int_as_float(a0.y) * x[a0.x * D + lane];
        s1 += __int_as_float(a1.y) * x[a1.x * D + lane];
        s2 += __int_as_float(a2.y) * x[a2.x * D + lane];
        s3 += __int_as_float(a3.y) * x[a3.x * D + lane];
        s4 += __int_as_float(a4.y) * x[a4.x * D + lane];
        s5 += __int_as_float(a5.y) * x[a5.x * D + lane];
        s6 += __int_as_float(a6.y) * x[a6.x * D + lane];
        s7 += __int_as_float(a7.y) * x[a7.x * D + lane];
    }
    for (; i < e; ++i) {
        int2 a = colval[i];
        s0 += __int_as_float(a.y) * x[a.x * D + lane];
    }
    float sum = ((s0 + s1) + (s2 + s3)) + ((s4 + s5) + (s6 + s7));
    int idx = row * D + lane;
    y[idx] = sum;
    float a = acc[idx] + sum;
    acc[idx] = LAST ? a * 0.25f : a;
}

extern "C" void kernel_launch(void* const* d_in, const int* in_sizes, int n_in,
                              void* d_out, int out_size, void* d_ws, size_t ws_size,
                              hipStream_t stream) {
    const int*   rows   = (const int*)d_in[0];
    const int*   cols   = (const int*)d_in[1];
    const float* vals   = (const float*)d_in[2];
    const float* user_w = (const float*)d_in[3];
    const float* item_w = (const float*)d_in[4];

    float* acc = (float*)d_out;

    // ws layout (16B alignment maintained):
    //   x (38.4MB) | y (38.4MB) | colval (76.8MB) |
    //   bcounts[B2] | bstart[B2+1] | bfill[B2] | row_start[NN+4 pad]
    // temp (76.8MB) aliases x|y — build runs before init_x_acc.
    float* x = (float*)d_ws;
    float* y = x + (size_t)TOTAL;
    int2*  temp = (int2*)d_ws;
    int2*  colval = (int2*)(y + (size_t)TOTAL);
    int*   bcounts = (int*)(colval + (size_t)NE);
    int*   bstart = bcounts + B2;                    // B2+1 entries
    int*   bfill = bstart + (B2 + 1);
    int*   row_start = bfill + B2;                   // NN+1 entries (+pad)

    const int vec_blocks   = (TOTAL / 4 + 255) / 256;   // 9375
    const int partA_blocks = (NE + EPB_A - 1) / EPB_A;  // 586
    const int row_blocks   = (NN + 7) / 8;              // 37500

    // Build exact CSR (bucket-granular counting; per-row offsets emitted in
    // sort_bucket2 — no 300K-bin global histogram, no 300K-element scan)
    hipMemsetAsync(bcounts, 0, (size_t)B2 * sizeof(int), stream);
    bucket_hist<<<NB_H, TPB_H, 0, stream>>>((const int4*)rows, bcounts);
    scan_buckets<<<1, 1024, 0, stream>>>(bcounts, bstart, bfill);
    partition_edges<<<partA_blocks, TPB_A, 0, stream>>>(
        (const int4*)rows, (const int4*)cols, (const float4*)vals, bfill, temp);
    sort_bucket2<<<B2, 256, 0, stream>>>(bstart, temp, row_start, colval);

    // Embeddings + accumulator (after build: temp aliases x|y)
    init_x_acc<<<vec_blocks, 256, 0, stream>>>(
        (const float4*)user_w, (const float4*)item_w, (float4*)x, (float4*)acc);

    // 3 propagation layers, atomic-free
    spmm_csr<false><<<row_blocks, 256, 0, stream>>>(row_start, colval, x, y, acc);
    spmm_csr<false><<<row_blocks, 256, 0, stream>>>(row_start, colval, y, x, acc);
    spmm_csr<true ><<<row_blocks, 256, 0, stream>>>(row_start, colval, x, y, acc);
}

// Round 3
// 932.240 us; speedup vs baseline: 1.4208x; 1.0400x over previous
//
#include <hip/hip_runtime.h>
#include <hip/hip_fp16.h>
#include <stdint.h>

#define NUM_USERS 200000
#define NUM_ITEMS 100000
#define NN (NUM_USERS + NUM_ITEMS)   // 300000
#define D 32
#define NE 9600000
#define TOTAL (NN * D)               // 9,600,000 elements

#define RPB2 128                     // rows per fine bucket
#define B2 ((NN + RPB2 - 1) / RPB2)  // 2344 buckets; region == CSR slice of 128 rows
#define CAP 5120                     // LDS stage capacity (mean 4096, sigma ~64)

#define TPB_A 1024                   // partition block size
#define EPT 16                       // edges per thread in partition
#define EPB_A (TPB_A * EPT)          // 16384 edges per block

#define TPB_H 1024                   // bucket-hist block size
#define EPT_H 32                     // edges per thread in bucket-hist
#define EPB_H (TPB_H * EPT_H)        // 32768 edges per block
#define NB_H ((NE + EPB_H - 1) / EPB_H)  // 293 blocks

// ---------------------------------------------------------------------------
// init: acc = concat(user_w, item_w) in fp32; xh = fp16 copy for the gather
// path. Runs AFTER the CSR build (build's temp aliases the xh|yh workspace).
__global__ __launch_bounds__(256) void init_x_acc(
    const float4* __restrict__ user_w, const float4* __restrict__ item_w,
    ushort4* __restrict__ xh, float4* __restrict__ acc) {
    int i = blockIdx.x * 256 + threadIdx.x;
    const int total4 = TOTAL / 4;
    const int ub4 = (NUM_USERS * D) / 4;
    if (i < total4) {
        float4 v = (i < ub4) ? user_w[i] : item_w[i - ub4];
        acc[i] = v;
        ushort4 h;
        h.x = __half_as_ushort(__float2half(v.x));
        h.y = __half_as_ushort(__float2half(v.y));
        h.z = __half_as_ushort(__float2half(v.z));
        h.w = __half_as_ushort(__float2half(v.w));
        xh[i] = h;
    }
}

// ---------------------------------------------------------------------------
// Bucket-granular degree histogram, LDS-privatized.
__global__ __launch_bounds__(TPB_H) void bucket_hist(
    const int4* __restrict__ rows4, int* __restrict__ bcounts) {
    __shared__ int hist[B2];                         // 9376 B
    int tid = threadIdx.x;
    for (int i = tid; i < B2; i += TPB_H) hist[i] = 0;
    __syncthreads();
    int base4 = blockIdx.x * (EPB_H / 4);
    #pragma unroll
    for (int k = 0; k < EPT_H / 4; ++k) {
        int i4 = base4 + k * TPB_H + tid;
        if (i4 < NE / 4) {
            int4 r = rows4[i4];
            atomicAdd(&hist[r.x >> 7], 1);
            atomicAdd(&hist[r.y >> 7], 1);
            atomicAdd(&hist[r.z >> 7], 1);
            atomicAdd(&hist[r.w >> 7], 1);
        }
    }
    __syncthreads();
    for (int b = tid; b < B2; b += TPB_H) {
        int c = hist[b];
        if (c) atomicAdd(&bcounts[b], c);
    }
}

// ---------------------------------------------------------------------------
// Single-block exclusive scan of the 2344 bucket counts -> bstart, bfill.
__global__ __launch_bounds__(1024) void scan_buckets(
    const int* __restrict__ bcounts, int* __restrict__ bstart,
    int* __restrict__ bfill) {
    __shared__ int lds[1024];
    int t = threadIdx.x;
    int v[4];
    int s = 0;
    #pragma unroll
    for (int k = 0; k < 4; ++k) {
        int b = t * 4 + k;
        v[k] = (b < B2) ? bcounts[b] : 0;
        s += v[k];
    }
    lds[t] = s;
    __syncthreads();
    for (int off = 1; off < 1024; off <<= 1) {
        int u = (t >= off) ? lds[t - off] : 0;
        __syncthreads();
        lds[t] += u;
        __syncthreads();
    }
    int ex = lds[t] - s;                             // exclusive prefix of chunk
    #pragma unroll
    for (int k = 0; k < 4; ++k) {
        int b = t * 4 + k;
        if (b < B2) { bstart[b] = ex; bfill[b] = ex; }
        ex += v[k];
    }
    if (t == 1023) bstart[B2] = ex;                  // == NE
}

// ---------------------------------------------------------------------------
// Pass A: block-privatized counting-split of edges into the 2344 bucket
// regions of temp. Phase 1 packs (bucket<<20 | row_local<<13 | rank) into ONE
// UNSIGNED word (12+7+13 = 32 bits — signed int overflowed at bucket>=2048,
// the R2 crash), so phase 2 only re-reads cols+vals (rows pass saved).
// rank < 8192 guaranteed for uniform data (observed max ~30 per block-bucket).
__global__ __launch_bounds__(TPB_A) void partition_edges(
    const int4* __restrict__ rows4, const int4* __restrict__ cols4,
    const float4* __restrict__ vals4, int* __restrict__ bfill,
    int2* __restrict__ temp) {
    __shared__ int hist[B2];                         // 9376 B
    int tid = threadIdx.x;
    for (int i = tid; i < B2; i += TPB_A) hist[i] = 0;
    __syncthreads();

    int base4 = blockIdx.x * (EPB_A / 4);
    uint32_t brank[EPT];                             // bucket<<20|rl<<13|rank

    #pragma unroll
    for (int k = 0; k < EPT / 4; ++k) {
        int i4 = base4 + k * TPB_A + tid;
        if (i4 < NE / 4) {
            int4 r = rows4[i4];
            uint32_t b0 = (uint32_t)r.x >> 7, b1 = (uint32_t)r.y >> 7;
            uint32_t b2 = (uint32_t)r.z >> 7, b3 = (uint32_t)r.w >> 7;
            brank[k * 4 + 0] = (b0 << 20) | (uint32_t)((r.x & 127) << 13) | (uint32_t)atomicAdd(&hist[b0], 1);
            brank[k * 4 + 1] = (b1 << 20) | (uint32_t)((r.y & 127) << 13) | (uint32_t)atomicAdd(&hist[b1], 1);
            brank[k * 4 + 2] = (b2 << 20) | (uint32_t)((r.z & 127) << 13) | (uint32_t)atomicAdd(&hist[b2], 1);
            brank[k * 4 + 3] = (b3 << 20) | (uint32_t)((r.w & 127) << 13) | (uint32_t)atomicAdd(&hist[b3], 1);
        }
    }
    __syncthreads();
    for (int b = tid; b < B2; b += TPB_A) {          // reserve runs
        int c = hist[b];
        if (c) hist[b] = atomicAdd(&bfill[b], c);    // hist now holds base
    }
    __syncthreads();

    #pragma unroll
    for (int k = 0; k < EPT / 4; ++k) {
        int i4 = base4 + k * TPB_A + tid;
        if (i4 < NE / 4) {
            int4 c = cols4[i4];
            float4 v = vals4[i4];
            uint32_t br; int pos; int2 cv;
            br = brank[k * 4 + 0]; pos = hist[br >> 20] + (int)(br & 0x1FFFu);
            cv.x = (int)(((br >> 13) & 127u) << 19) | c.x; cv.y = __float_as_int(v.x); temp[pos] = cv;
            br = brank[k * 4 + 1]; pos = hist[br >> 20] + (int)(br & 0x1FFFu);
            cv.x = (int)(((br >> 13) & 127u) << 19) | c.y; cv.y = __float_as_int(v.y); temp[pos] = cv;
            br = brank[k * 4 + 2]; pos = hist[br >> 20] + (int)(br & 0x1FFFu);
            cv.x = (int)(((br >> 13) & 127u) << 19) | c.z; cv.y = __float_as_int(v.z); temp[pos] = cv;
            br = brank[k * 4 + 3]; pos = hist[br >> 20] + (int)(br & 0x1FFFu);
            cv.x = (int)(((br >> 13) & 127u) << 19) | c.w; cv.y = __float_as_int(v.w); temp[pos] = cv;
        }
    }
}

// ---------------------------------------------------------------------------
// Pass B: exact within-bucket counting sort through LDS, producing row_start.
__global__ __launch_bounds__(256) void sort_bucket2(
    const int* __restrict__ bstart, const int2* __restrict__ temp,
    int* __restrict__ row_start, int2* __restrict__ colval) {
    __shared__ int2 stage[CAP];                      // 40 KB
    __shared__ int lstart[RPB2];
    __shared__ int lfill[RPB2];
    int b = blockIdx.x;
    int row0 = b * RPB2;
    int rcount = NN - row0; if (rcount > RPB2) rcount = RPB2;
    int tid = threadIdx.x;
    int s = bstart[b];
    int count = bstart[b + 1] - s;

    if (tid < RPB2) lfill[tid] = 0;
    __syncthreads();

    // pass 1: per-row counts of this bucket's edges
    for (int i = tid; i < count; i += 256) {
        int rl = temp[s + i].x >> 19;
        atomicAdd(&lfill[rl], 1);
    }
    __syncthreads();

    // 128-wide Hillis-Steele scan -> exclusive per-row offsets
    int val = (tid < RPB2) ? lfill[tid] : 0;
    if (tid < RPB2) lstart[tid] = val;
    __syncthreads();
    for (int off = 1; off < RPB2; off <<= 1) {
        int u = (tid >= off && tid < RPB2) ? lstart[tid - off] : 0;
        __syncthreads();
        if (tid < RPB2) lstart[tid] += u;
        __syncthreads();
    }
    int ex = (tid < RPB2) ? lstart[tid] - val : 0;
    if (tid < RPB2) {
        lstart[tid] = ex;
        lfill[tid] = 0;                              // reset for rank pass
        if (tid < rcount) row_start[row0 + tid] = s + ex;
    }
    if (b == 0 && tid == 0) row_start[NN] = NE;
    __syncthreads();

    // pass 2: rank + stage + coalesced flush
    if (count <= CAP) {
        for (int i = tid; i < count; i += 256) {
            int2 e = temp[s + i];
            int rl = e.x >> 19;
            int pos = lstart[rl] + atomicAdd(&lfill[rl], 1);
            stage[pos] = make_int2(e.x & 0x7FFFF, e.y);
        }
        __syncthreads();
        for (int i = tid; i < count; i += 256) colval[s + i] = stage[i];
    } else {
        for (int i = tid; i < count; i += 256) {
            int2 e = temp[s + i];
            int rl = e.x >> 19;
            int pos = lstart[rl] + atomicAdd(&lfill[rl], 1);
            colval[s + pos] = make_int2(e.x & 0x7FFFF, e.y);
        }
    }
}

// ---------------------------------------------------------------------------
// Atomic-free SpMM, fp16 gather path: one 32-lane half-wave per row
// (lane = feature d). x rows are 64B fp16 granules (half the fetch of fp32);
// products and accumulator stay fp32. Fused y_h store (skipped on LAST) +
// acc += sum (and *0.25 on the last layer).
template <bool LAST>
__global__ __launch_bounds__(256) void spmm_csr(
    const int* __restrict__ row_start, const int2* __restrict__ colval,
    const __half* __restrict__ xh, __half* __restrict__ yh,
    float* __restrict__ acc) {
    int lane = threadIdx.x & 31;
    int row = blockIdx.x * 8 + (threadIdx.x >> 5);
    if (row >= NN) return;
    int s = row_start[row];
    int e = row_start[row + 1];
    float s0 = 0.f, s1 = 0.f, s2 = 0.f, s3 = 0.f;
    float s4 = 0.f, s5 = 0.f, s6 = 0.f, s7 = 0.f;
    int i = s;
    for (; i + 7 < e; i += 8) {
        int2 a0 = colval[i];
        int2 a1 = colval[i + 1];
        int2 a2 = colval[i + 2];
        int2 a3 = colval[i + 3];
        int2 a4 = colval[i + 4];
        int2 a5 = colval[i + 5];
        int2 a6 = colval[i + 6];
        int2 a7 = colval[i + 7];
        s0 += __int_as_float(a0.y) * __half2float(xh[a0.x * D + lane]);
        s1 += __int_as_float(a1.y) * __half2float(xh[a1.x * D + lane]);
        s2 += __int_as_float(a2.y) * __half2float(xh[a2.x * D + lane]);
        s3 += __int_as_float(a3.y) * __half2float(xh[a3.x * D + lane]);
        s4 += __int_as_float(a4.y) * __half2float(xh[a4.x * D + lane]);
        s5 += __int_as_float(a5.y) * __half2float(xh[a5.x * D + lane]);
        s6 += __int_as_float(a6.y) * __half2float(xh[a6.x * D + lane]);
        s7 += __int_as_float(a7.y) * __half2float(xh[a7.x * D + lane]);
    }
    for (; i < e; ++i) {
        int2 a = colval[i];
        s0 += __int_as_float(a.y) * __half2float(xh[a.x * D + lane]);
    }
    float sum = ((s0 + s1) + (s2 + s3)) + ((s4 + s5) + (s6 + s7));
    int idx = row * D + lane;
    if (!LAST) yh[idx] = __float2half(sum);
    float a = acc[idx] + sum;
    acc[idx] = LAST ? a * 0.25f : a;
}

extern "C" void kernel_launch(void* const* d_in, const int* in_sizes, int n_in,
                              void* d_out, int out_size, void* d_ws, size_t ws_size,
                              hipStream_t stream) {
    const int*   rows   = (const int*)d_in[0];
    const int*   cols   = (const int*)d_in[1];
    const float* vals   = (const float*)d_in[2];
    const float* user_w = (const float*)d_in[3];
    const float* item_w = (const float*)d_in[4];

    float* acc = (float*)d_out;                      // fp32 output/accumulator

    // ws layout (16B alignment maintained):
    //   [0, 76.8MB): build-time temp; post-build xh (19.2MB) | yh (19.2MB)
    //   colval (76.8MB) | bcounts[B2] | bstart[B2+1] | bfill[B2] | row_start[NN+1]
    __half* xh = (__half*)d_ws;
    __half* yh = xh + (size_t)TOTAL;
    int2*  temp = (int2*)d_ws;
    int2*  colval = (int2*)((char*)d_ws + 2ull * (size_t)TOTAL * sizeof(float));
    int*   bcounts = (int*)(colval + (size_t)NE);
    int*   bstart = bcounts + B2;                    // B2+1 entries
    int*   bfill = bstart + (B2 + 1);
    int*   row_start = bfill + B2;                   // NN+1 entries (+pad)

    const int vec_blocks   = (TOTAL / 4 + 255) / 256;   // 9375
    const int partA_blocks = (NE + EPB_A - 1) / EPB_A;  // 586
    const int row_blocks   = (NN + 7) / 8;              // 37500

    // Build exact CSR
    hipMemsetAsync(bcounts, 0, (size_t)B2 * sizeof(int), stream);
    bucket_hist<<<NB_H, TPB_H, 0, stream>>>((const int4*)rows, bcounts);
    scan_buckets<<<1, 1024, 0, stream>>>(bcounts, bstart, bfill);
    partition_edges<<<partA_blocks, TPB_A, 0, stream>>>(
        (const int4*)rows, (const int4*)cols, (const float4*)vals, bfill, temp);
    sort_bucket2<<<B2, 256, 0, stream>>>(bstart, temp, row_start, colval);

    // Embeddings + accumulator (after build: temp aliases xh|yh)
    init_x_acc<<<vec_blocks, 256, 0, stream>>>(
        (const float4*)user_w, (const float4*)item_w, (ushort4*)xh, (float4*)acc);

    // 3 propagation layers, atomic-free, fp16 gather
    spmm_csr<false><<<row_blocks, 256, 0, stream>>>(row_start, colval, xh, yh, acc);
    spmm_csr<false><<<row_blocks, 256, 0, stream>>>(row_start, colval, yh, xh, acc);
    spmm_csr<true ><<<row_blocks, 256, 0, stream>>>(row_start, colval, xh, yh, acc);
}

// Round 4
// 868.806 us; speedup vs baseline: 1.5246x; 1.0730x over previous
//
#include <hip/hip_runtime.h>
#include <hip/hip_fp16.h>
#include <stdint.h>

#define NUM_USERS 200000
#define NUM_ITEMS 100000
#define NN (NUM_USERS + NUM_ITEMS)   // 300000
#define D 32
#define NE 9600000
#define TOTAL (NN * D)               // 9,600,000 elements

#define RPB2 128                     // rows per fine bucket
#define B2 ((NN + RPB2 - 1) / RPB2)  // 2344 buckets; region == CSR slice of 128 rows
#define CAP 5120                     // LDS stage capacity (mean 4096, sigma ~64)

#define TPB_A 1024                   // partition block size
#define EPT 16                       // edges per thread in partition
#define EPB_A (TPB_A * EPT)          // 16384 edges per block

#define TPB_H 1024                   // bucket-hist block size
#define EPT_H 32                     // edges per thread in bucket-hist
#define EPB_H (TPB_H * EPT_H)        // 32768 edges per block
#define NB_H ((NE + EPB_H - 1) / EPB_H)  // 293 blocks

// ---------------------------------------------------------------------------
// init: acc = concat(user_w, item_w) in fp32; xh = fp16 copy for the gather
// path. Runs AFTER the CSR build (build's temp aliases the xh|yh workspace).
__global__ __launch_bounds__(256) void init_x_acc(
    const float4* __restrict__ user_w, const float4* __restrict__ item_w,
    ushort4* __restrict__ xh, float4* __restrict__ acc) {
    int i = blockIdx.x * 256 + threadIdx.x;
    const int total4 = TOTAL / 4;
    const int ub4 = (NUM_USERS * D) / 4;
    if (i < total4) {
        float4 v = (i < ub4) ? user_w[i] : item_w[i - ub4];
        acc[i] = v;
        ushort4 h;
        h.x = __half_as_ushort(__float2half(v.x));
        h.y = __half_as_ushort(__float2half(v.y));
        h.z = __half_as_ushort(__float2half(v.z));
        h.w = __half_as_ushort(__float2half(v.w));
        xh[i] = h;
    }
}

// ---------------------------------------------------------------------------
// Bucket-granular degree histogram, LDS-privatized.
__global__ __launch_bounds__(TPB_H) void bucket_hist(
    const int4* __restrict__ rows4, int* __restrict__ bcounts) {
    __shared__ int hist[B2];                         // 9376 B
    int tid = threadIdx.x;
    for (int i = tid; i < B2; i += TPB_H) hist[i] = 0;
    __syncthreads();
    int base4 = blockIdx.x * (EPB_H / 4);
    #pragma unroll
    for (int k = 0; k < EPT_H / 4; ++k) {
        int i4 = base4 + k * TPB_H + tid;
        if (i4 < NE / 4) {
            int4 r = rows4[i4];
            atomicAdd(&hist[r.x >> 7], 1);
            atomicAdd(&hist[r.y >> 7], 1);
            atomicAdd(&hist[r.z >> 7], 1);
            atomicAdd(&hist[r.w >> 7], 1);
        }
    }
    __syncthreads();
    for (int b = tid; b < B2; b += TPB_H) {
        int c = hist[b];
        if (c) atomicAdd(&bcounts[b], c);
    }
}

// ---------------------------------------------------------------------------
// Single-block exclusive scan of the 2344 bucket counts -> bstart, bfill.
__global__ __launch_bounds__(1024) void scan_buckets(
    const int* __restrict__ bcounts, int* __restrict__ bstart,
    int* __restrict__ bfill) {
    __shared__ int lds[1024];
    int t = threadIdx.x;
    int v[4];
    int s = 0;
    #pragma unroll
    for (int k = 0; k < 4; ++k) {
        int b = t * 4 + k;
        v[k] = (b < B2) ? bcounts[b] : 0;
        s += v[k];
    }
    lds[t] = s;
    __syncthreads();
    for (int off = 1; off < 1024; off <<= 1) {
        int u = (t >= off) ? lds[t - off] : 0;
        __syncthreads();
        lds[t] += u;
        __syncthreads();
    }
    int ex = lds[t] - s;                             // exclusive prefix of chunk
    #pragma unroll
    for (int k = 0; k < 4; ++k) {
        int b = t * 4 + k;
        if (b < B2) { bstart[b] = ex; bfill[b] = ex; }
        ex += v[k];
    }
    if (t == 1023) bstart[B2] = ex;                  // == NE
}

// ---------------------------------------------------------------------------
// Pass A: block-privatized counting-split of edges into the 2344 bucket
// regions of temp. Phase 1 packs (bucket<<20 | row_local<<13 | rank) into ONE
// UNSIGNED word (12+7+13 = 32 bits), so phase 2 only re-reads cols+vals.
__global__ __launch_bounds__(TPB_A) void partition_edges(
    const int4* __restrict__ rows4, const int4* __restrict__ cols4,
    const float4* __restrict__ vals4, int* __restrict__ bfill,
    int2* __restrict__ temp) {
    __shared__ int hist[B2];                         // 9376 B
    int tid = threadIdx.x;
    for (int i = tid; i < B2; i += TPB_A) hist[i] = 0;
    __syncthreads();

    int base4 = blockIdx.x * (EPB_A / 4);
    uint32_t brank[EPT];                             // bucket<<20|rl<<13|rank

    #pragma unroll
    for (int k = 0; k < EPT / 4; ++k) {
        int i4 = base4 + k * TPB_A + tid;
        if (i4 < NE / 4) {
            int4 r = rows4[i4];
            uint32_t b0 = (uint32_t)r.x >> 7, b1 = (uint32_t)r.y >> 7;
            uint32_t b2 = (uint32_t)r.z >> 7, b3 = (uint32_t)r.w >> 7;
            brank[k * 4 + 0] = (b0 << 20) | (uint32_t)((r.x & 127) << 13) | (uint32_t)atomicAdd(&hist[b0], 1);
            brank[k * 4 + 1] = (b1 << 20) | (uint32_t)((r.y & 127) << 13) | (uint32_t)atomicAdd(&hist[b1], 1);
            brank[k * 4 + 2] = (b2 << 20) | (uint32_t)((r.z & 127) << 13) | (uint32_t)atomicAdd(&hist[b2], 1);
            brank[k * 4 + 3] = (b3 << 20) | (uint32_t)((r.w & 127) << 13) | (uint32_t)atomicAdd(&hist[b3], 1);
        }
    }
    __syncthreads();
    for (int b = tid; b < B2; b += TPB_A) {          // reserve runs
        int c = hist[b];
        if (c) hist[b] = atomicAdd(&bfill[b], c);    // hist now holds base
    }
    __syncthreads();

    #pragma unroll
    for (int k = 0; k < EPT / 4; ++k) {
        int i4 = base4 + k * TPB_A + tid;
        if (i4 < NE / 4) {
            int4 c = cols4[i4];
            float4 v = vals4[i4];
            uint32_t br; int pos; int2 cv;
            br = brank[k * 4 + 0]; pos = hist[br >> 20] + (int)(br & 0x1FFFu);
            cv.x = (int)(((br >> 13) & 127u) << 19) | c.x; cv.y = __float_as_int(v.x); temp[pos] = cv;
            br = brank[k * 4 + 1]; pos = hist[br >> 20] + (int)(br & 0x1FFFu);
            cv.x = (int)(((br >> 13) & 127u) << 19) | c.y; cv.y = __float_as_int(v.y); temp[pos] = cv;
            br = brank[k * 4 + 2]; pos = hist[br >> 20] + (int)(br & 0x1FFFu);
            cv.x = (int)(((br >> 13) & 127u) << 19) | c.z; cv.y = __float_as_int(v.z); temp[pos] = cv;
            br = brank[k * 4 + 3]; pos = hist[br >> 20] + (int)(br & 0x1FFFu);
            cv.x = (int)(((br >> 13) & 127u) << 19) | c.w; cv.y = __float_as_int(v.w); temp[pos] = cv;
        }
    }
}

// ---------------------------------------------------------------------------
// Pass B: exact within-bucket counting sort through LDS, producing row_start.
__global__ __launch_bounds__(256) void sort_bucket2(
    const int* __restrict__ bstart, const int2* __restrict__ temp,
    int* __restrict__ row_start, int2* __restrict__ colval) {
    __shared__ int2 stage[CAP];                      // 40 KB
    __shared__ int lstart[RPB2];
    __shared__ int lfill[RPB2];
    int b = blockIdx.x;
    int row0 = b * RPB2;
    int rcount = NN - row0; if (rcount > RPB2) rcount = RPB2;
    int tid = threadIdx.x;
    int s = bstart[b];
    int count = bstart[b + 1] - s;

    if (tid < RPB2) lfill[tid] = 0;
    __syncthreads();

    // pass 1: per-row counts of this bucket's edges
    for (int i = tid; i < count; i += 256) {
        int rl = temp[s + i].x >> 19;
        atomicAdd(&lfill[rl], 1);
    }
    __syncthreads();

    // 128-wide Hillis-Steele scan -> exclusive per-row offsets
    int val = (tid < RPB2) ? lfill[tid] : 0;
    if (tid < RPB2) lstart[tid] = val;
    __syncthreads();
    for (int off = 1; off < RPB2; off <<= 1) {
        int u = (tid >= off && tid < RPB2) ? lstart[tid - off] : 0;
        __syncthreads();
        if (tid < RPB2) lstart[tid] += u;
        __syncthreads();
    }
    int ex = (tid < RPB2) ? lstart[tid] - val : 0;
    if (tid < RPB2) {
        lstart[tid] = ex;
        lfill[tid] = 0;                              // reset for rank pass
        if (tid < rcount) row_start[row0 + tid] = s + ex;
    }
    if (b == 0 && tid == 0) row_start[NN] = NE;
    __syncthreads();

    // pass 2: rank + stage + coalesced flush
    if (count <= CAP) {
        for (int i = tid; i < count; i += 256) {
            int2 e = temp[s + i];
            int rl = e.x >> 19;
            int pos = lstart[rl] + atomicAdd(&lfill[rl], 1);
            stage[pos] = make_int2(e.x & 0x7FFFF, e.y);
        }
        __syncthreads();
        for (int i = tid; i < count; i += 256) colval[s + i] = stage[i];
    } else {
        for (int i = tid; i < count; i += 256) {
            int2 e = temp[s + i];
            int rl = e.x >> 19;
            int pos = lstart[rl] + atomicAdd(&lfill[rl], 1);
            colval[s + pos] = make_int2(e.x & 0x7FFFF, e.y);
        }
    }
}

// ---------------------------------------------------------------------------
// Atomic-free SpMM, wide-gather layout: ONE wave64 per row.
//   grp = lane>>3  : edge slot (8 edges in flight per wave instruction)
//   fq  = lane&7   : feature quad (lane loads ushort4 = features 4fq..4fq+3)
// One gather instruction covers 8 edges x 8B = same 64B lines as before but
// 8x fewer VMEM instructions; colval is loaded group-indexed (1 dwordx2 per
// 8 edges instead of a broadcast load per edge). 16-edge main step = two
// independent gather chains. Epilogue: 3-round shfl_xor butterfly over edge
// slots; lanes 0-7 store the row (yh skipped on LAST, acc fused *0.25).
template <bool LAST>
__global__ __launch_bounds__(256) void spmm_csr(
    const int* __restrict__ row_start, const int2* __restrict__ colval,
    const __half* __restrict__ xh, __half* __restrict__ yh,
    float* __restrict__ acc) {
    int lane = threadIdx.x & 63;
    int grp = lane >> 3;
    int fq = lane & 7;
    int row = (blockIdx.x * 256 + threadIdx.x) >> 6;
    if (row >= NN) return;
    int s = row_start[row];
    int e = row_start[row + 1];
    if (s == e) {                                    // empty row (paranoia)
        if (lane < 8) {
            size_t idx = (size_t)row * D + lane * 4;
            if (!LAST) *(uint2*)(yh + idx) = make_uint2(0u, 0u);
            float4 av = *(const float4*)(acc + idx);
            if (LAST) { av.x *= 0.25f; av.y *= 0.25f; av.z *= 0.25f; av.w *= 0.25f; }
            *(float4*)(acc + idx) = av;
        }
        return;
    }
    float a0 = 0.f, a1 = 0.f, a2 = 0.f, a3 = 0.f;
    float b0 = 0.f, b1 = 0.f, b2 = 0.f, b3 = 0.f;
    int i = s;
    for (; i + 16 <= e; i += 16) {
        int2 cvA = colval[i + grp];
        int2 cvB = colval[i + 8 + grp];
        uint2 hA = *(const uint2*)(xh + (size_t)cvA.x * D + fq * 4);
        uint2 hB = *(const uint2*)(xh + (size_t)cvB.x * D + fq * 4);
        float vA = __int_as_float(cvA.y);
        float vB = __int_as_float(cvB.y);
        float2 fA0 = __half22float2(*(__half2*)&hA.x);
        float2 fA1 = __half22float2(*(__half2*)&hA.y);
        float2 fB0 = __half22float2(*(__half2*)&hB.x);
        float2 fB1 = __half22float2(*(__half2*)&hB.y);
        a0 += vA * fA0.x; a1 += vA * fA0.y; a2 += vA * fA1.x; a3 += vA * fA1.y;
        b0 += vB * fB0.x; b1 += vB * fB0.y; b2 += vB * fB1.x; b3 += vB * fB1.y;
    }
    if (i < e) {                                     // masked tail, 1..15 edges
        int iA = i + grp;
        int iB = i + 8 + grp;
        int cA = (iA < e) ? iA : (e - 1);            // clamp: stay on hot lines
        int cB = (iB < e) ? iB : (e - 1);
        int2 cvA = colval[cA];
        int2 cvB = colval[cB];
        uint2 hA = *(const uint2*)(xh + (size_t)cvA.x * D + fq * 4);
        uint2 hB = *(const uint2*)(xh + (size_t)cvB.x * D + fq * 4);
        float vA = (iA < e) ? __int_as_float(cvA.y) : 0.f;
        float vB = (iB < e) ? __int_as_float(cvB.y) : 0.f;
        float2 fA0 = __half22float2(*(__half2*)&hA.x);
        float2 fA1 = __half22float2(*(__half2*)&hA.y);
        float2 fB0 = __half22float2(*(__half2*)&hB.x);
        float2 fB1 = __half22float2(*(__half2*)&hB.y);
        a0 += vA * fA0.x; a1 += vA * fA0.y; a2 += vA * fA1.x; a3 += vA * fA1.y;
        b0 += vB * fB0.x; b1 += vB * fB0.y; b2 += vB * fB1.x; b3 += vB * fB1.y;
    }
    a0 += b0; a1 += b1; a2 += b2; a3 += b3;
    // butterfly over edge-slot bits (lane bits 3,4,5)
    #pragma unroll
    for (int m = 8; m <= 32; m <<= 1) {
        a0 += __shfl_xor(a0, m, 64);
        a1 += __shfl_xor(a1, m, 64);
        a2 += __shfl_xor(a2, m, 64);
        a3 += __shfl_xor(a3, m, 64);
    }
    if (lane < 8) {                                  // grp==0, fq==lane
        size_t idx = (size_t)row * D + lane * 4;
        if (!LAST) {
            __half2 h01 = __float22half2_rn(make_float2(a0, a1));
            __half2 h23 = __float22half2_rn(make_float2(a2, a3));
            *(uint2*)(yh + idx) =
                make_uint2(*(uint32_t*)&h01, *(uint32_t*)&h23);
        }
        float4 av = *(const float4*)(acc + idx);
        av.x += a0; av.y += a1; av.z += a2; av.w += a3;
        if (LAST) { av.x *= 0.25f; av.y *= 0.25f; av.z *= 0.25f; av.w *= 0.25f; }
        *(float4*)(acc + idx) = av;
    }
}

extern "C" void kernel_launch(void* const* d_in, const int* in_sizes, int n_in,
                              void* d_out, int out_size, void* d_ws, size_t ws_size,
                              hipStream_t stream) {
    const int*   rows   = (const int*)d_in[0];
    const int*   cols   = (const int*)d_in[1];
    const float* vals   = (const float*)d_in[2];
    const float* user_w = (const float*)d_in[3];
    const float* item_w = (const float*)d_in[4];

    float* acc = (float*)d_out;                      // fp32 output/accumulator

    // ws layout (16B alignment maintained):
    //   [0, 76.8MB): build-time temp; post-build xh (19.2MB) | yh (19.2MB)
    //   colval (76.8MB) | bcounts[B2] | bstart[B2+1] | bfill[B2] | row_start[NN+1]
    __half* xh = (__half*)d_ws;
    __half* yh = xh + (size_t)TOTAL;
    int2*  temp = (int2*)d_ws;
    int2*  colval = (int2*)((char*)d_ws + 2ull * (size_t)TOTAL * sizeof(float));
    int*   bcounts = (int*)(colval + (size_t)NE);
    int*   bstart = bcounts + B2;                    // B2+1 entries
    int*   bfill = bstart + (B2 + 1);
    int*   row_start = bfill + B2;                   // NN+1 entries (+pad)

    const int vec_blocks   = (TOTAL / 4 + 255) / 256;   // 9375
    const int partA_blocks = (NE + EPB_A - 1) / EPB_A;  // 586
    const int row_blocks   = (NN + 3) / 4;              // 75000 (1 wave64/row)

    // Build exact CSR
    hipMemsetAsync(bcounts, 0, (size_t)B2 * sizeof(int), stream);
    bucket_hist<<<NB_H, TPB_H, 0, stream>>>((const int4*)rows, bcounts);
    scan_buckets<<<1, 1024, 0, stream>>>(bcounts, bstart, bfill);
    partition_edges<<<partA_blocks, TPB_A, 0, stream>>>(
        (const int4*)rows, (const int4*)cols, (const float4*)vals, bfill, temp);
    sort_bucket2<<<B2, 256, 0, stream>>>(bstart, temp, row_start, colval);

    // Embeddings + accumulator (after build: temp aliases xh|yh)
    init_x_acc<<<vec_blocks, 256, 0, stream>>>(
        (const float4*)user_w, (const float4*)item_w, (ushort4*)xh, (float4*)acc);

    // 3 propagation layers, atomic-free, wide fp16 gather
    spmm_csr<false><<<row_blocks, 256, 0, stream>>>(row_start, colval, xh, yh, acc);
    spmm_csr<false><<<row_blocks, 256, 0, stream>>>(row_start, colval, yh, xh, acc);
    spmm_csr<true ><<<row_blocks, 256, 0, stream>>>(row_start, colval, xh, yh, acc);
}

// Round 5
// 826.249 us; speedup vs baseline: 1.6031x; 1.0515x over previous
//
#include <hip/hip_runtime.h>
#include <hip/hip_fp16.h>
#include <stdint.h>

#define NUM_USERS 200000
#define NUM_ITEMS 100000
#define NN (NUM_USERS + NUM_ITEMS)   // 300000
#define D 32
#define NE 9600000
#define TOTAL (NN * D)               // 9,600,000 elements

#define RPB2 128                     // rows per fine bucket
#define B2 ((NN + RPB2 - 1) / RPB2)  // 2344 fine buckets
#define CAP 5120                     // LDS stage capacity in sort (mean 4096, sigma ~64)

#define CSH 12                       // coarse bucket = row >> 12 (4096 rows)
#define NC ((NN + (1 << CSH) - 1) >> CSH)   // 74 coarse buckets
#define FPC 32                       // fine buckets per coarse (4096/128)
#define BPC 9                        // fine-pass blocks per coarse region

#define TPB_A 1024                   // partition block size
#define EPT 16                       // edges per thread in partition
#define EPB_A (TPB_A * EPT)          // 16384 edges per block

#define TPB_H 1024                   // bucket-hist block size
#define EPT_H 32
#define EPB_H (TPB_H * EPT_H)        // 32768 edges per block
#define NB_H ((NE + EPB_H - 1) / EPB_H)  // 293 blocks

// ---------------------------------------------------------------------------
// init: acc = concat(user_w, item_w) in fp32; xh = fp16 copy for the gather
// path. Runs AFTER the CSR build (build's temp1 aliases the xh|yh workspace).
__global__ __launch_bounds__(256) void init_x_acc(
    const float4* __restrict__ user_w, const float4* __restrict__ item_w,
    ushort4* __restrict__ xh, float4* __restrict__ acc) {
    int i = blockIdx.x * 256 + threadIdx.x;
    const int total4 = TOTAL / 4;
    const int ub4 = (NUM_USERS * D) / 4;
    if (i < total4) {
        float4 v = (i < ub4) ? user_w[i] : item_w[i - ub4];
        acc[i] = v;
        ushort4 h;
        h.x = __half_as_ushort(__float2half(v.x));
        h.y = __half_as_ushort(__float2half(v.y));
        h.z = __half_as_ushort(__float2half(v.z));
        h.w = __half_as_ushort(__float2half(v.w));
        xh[i] = h;
    }
}

// ---------------------------------------------------------------------------
// Fine-bucket degree histogram, LDS-privatized (needed for bstart regions).
__global__ __launch_bounds__(TPB_H) void bucket_hist(
    const int4* __restrict__ rows4, int* __restrict__ bcounts) {
    __shared__ int hist[B2];                         // 9376 B
    int tid = threadIdx.x;
    for (int i = tid; i < B2; i += TPB_H) hist[i] = 0;
    __syncthreads();
    int base4 = blockIdx.x * (EPB_H / 4);
    #pragma unroll
    for (int k = 0; k < EPT_H / 4; ++k) {
        int i4 = base4 + k * TPB_H + tid;
        if (i4 < NE / 4) {
            int4 r = rows4[i4];
            atomicAdd(&hist[r.x >> 7], 1);
            atomicAdd(&hist[r.y >> 7], 1);
            atomicAdd(&hist[r.z >> 7], 1);
            atomicAdd(&hist[r.w >> 7], 1);
        }
    }
    __syncthreads();
    for (int b = tid; b < B2; b += TPB_H) {
        int c = hist[b];
        if (c) atomicAdd(&bcounts[b], c);
    }
}

// ---------------------------------------------------------------------------
// Single-block exclusive scan of the 2344 fine counts -> bstart, bfill, and
// coarse fill counters cfill[c] = bstart[c*32] (consumed by partition_coarse).
__global__ __launch_bounds__(1024) void scan_buckets(
    const int* __restrict__ bcounts, int* __restrict__ bstart,
    int* __restrict__ bfill, int* __restrict__ cfill) {
    __shared__ int lds[1024];
    int t = threadIdx.x;
    int v[4];
    int s = 0;
    #pragma unroll
    for (int k = 0; k < 4; ++k) {
        int b = t * 4 + k;
        v[k] = (b < B2) ? bcounts[b] : 0;
        s += v[k];
    }
    lds[t] = s;
    __syncthreads();
    for (int off = 1; off < 1024; off <<= 1) {
        int u = (t >= off) ? lds[t - off] : 0;
        __syncthreads();
        lds[t] += u;
        __syncthreads();
    }
    int ex = lds[t] - s;                             // exclusive prefix of chunk
    #pragma unroll
    for (int k = 0; k < 4; ++k) {
        int b = t * 4 + k;
        if (b < B2) {
            bstart[b] = ex;
            bfill[b] = ex;
            if ((b & (FPC - 1)) == 0) cfill[b >> 5] = ex;
        }
        ex += v[k];
    }
    if (t == 1023) bstart[B2] = ex;                  // == NE
}

// ---------------------------------------------------------------------------
// Pass A1: coarse partition (74 buckets of 4096 rows). The edge's
// (key = (row&4095)<<19 | col, val) stays in registers; edges are sorted
// into a 128KB LDS stage in coarse order, then flushed POSITION-MAJOR so
// every wave store instruction is coalesced (runs avg 221 edges = 1.77KB)
// — this removes the 64-scattered-lines-per-store pattern that made the old
// single-level partition 3.9x write-amplified and latency-bound.
__global__ __launch_bounds__(TPB_A) void partition_coarse(
    const int4* __restrict__ rows4, const int4* __restrict__ cols4,
    const float4* __restrict__ vals4, int* __restrict__ cfill,
    int2* __restrict__ temp1) {
    __shared__ int2 stage[EPB_A];                    // 128 KB
    __shared__ int hist[NC];
    __shared__ int bnd[NC + 1];
    __shared__ int dlt[NC];
    __shared__ int sc[128];
    int tid = threadIdx.x;
    if (tid < NC) hist[tid] = 0;
    __syncthreads();

    int base4 = blockIdx.x * (EPB_A / 4);
    int keys[EPT]; int vls[EPT]; int crk[EPT];       // crk: coarse<<13|rank

    #pragma unroll
    for (int k = 0; k < EPT / 4; ++k) {
        int i4 = base4 + k * TPB_A + tid;
        if (i4 < NE / 4) {
            int4 r = rows4[i4];
            int4 c = cols4[i4];
            float4 v = vals4[i4];
            int c0 = r.x >> CSH, c1 = r.y >> CSH, c2 = r.z >> CSH, c3 = r.w >> CSH;
            keys[k*4+0] = ((r.x & 4095) << 19) | c.x; vls[k*4+0] = __float_as_int(v.x);
            crk[k*4+0] = (c0 << 13) | atomicAdd(&hist[c0], 1);
            keys[k*4+1] = ((r.y & 4095) << 19) | c.y; vls[k*4+1] = __float_as_int(v.y);
            crk[k*4+1] = (c1 << 13) | atomicAdd(&hist[c1], 1);
            keys[k*4+2] = ((r.z & 4095) << 19) | c.z; vls[k*4+2] = __float_as_int(v.z);
            crk[k*4+2] = (c2 << 13) | atomicAdd(&hist[c2], 1);
            keys[k*4+3] = ((r.w & 4095) << 19) | c.w; vls[k*4+3] = __float_as_int(v.w);
            crk[k*4+3] = (c3 << 13) | atomicAdd(&hist[c3], 1);
        }
    }
    __syncthreads();
    // scan the 74 counts (128-thread Hillis-Steele)
    if (tid < 128) sc[tid] = (tid < NC) ? hist[tid] : 0;
    __syncthreads();
    #pragma unroll
    for (int off = 1; off < 128; off <<= 1) {
        int u = (tid >= off && tid < 128) ? sc[tid - off] : 0;
        __syncthreads();
        if (tid < 128) sc[tid] += u;
        __syncthreads();
    }
    if (tid < NC) {
        int cnt = hist[tid];
        int ex = sc[tid] - cnt;
        bnd[tid] = ex;
        dlt[tid] = (cnt ? atomicAdd(&cfill[tid], cnt) : 0) - ex;
    }
    if (tid == 0) bnd[NC] = sc[NC - 1];
    __syncthreads();
    // stage in coarse-sorted order (LDS scatter)
    #pragma unroll
    for (int k = 0; k < EPT / 4; ++k) {
        int i4 = base4 + k * TPB_A + tid;
        if (i4 < NE / 4) {
            #pragma unroll
            for (int j = 0; j < 4; ++j) {
                int e = k * 4 + j;
                int p = bnd[crk[e] >> 13] + (crk[e] & 0x1FFF);
                stage[p] = make_int2(keys[e], vls[e]);
            }
        }
    }
    __syncthreads();
    // coalesced flush: consecutive positions -> consecutive global dests
    int ntot = bnd[NC];
    for (int j = tid; j < ntot; j += TPB_A) {
        int lo = 0, hi = NC;                         // bnd[lo] <= j < bnd[hi]
        while (hi - lo > 1) { int mid = (lo + hi) >> 1; if (bnd[mid] <= j) lo = mid; else hi = mid; }
        temp1[j + dlt[lo]] = stage[j];
    }
}

// ---------------------------------------------------------------------------
// Pass A2: fine partition within each coarse region (32 fine buckets).
// 9 blocks per coarse; same LDS-stage + coalesced-flush structure. Runs avg
// 512 edges = 4KB -> amplification ~1.03. Emits sort_bucket2's packing
// ((row&127)<<19 | col, val) directly into the colval region.
__global__ __launch_bounds__(TPB_A) void partition_fine(
    const int2* __restrict__ temp1, const int* __restrict__ bstart,
    int* __restrict__ bfill, int2* __restrict__ colval) {
    __shared__ int2 stage[EPB_A];                    // 128 KB
    __shared__ int hist[FPC];
    __shared__ int bnd[FPC + 1];
    __shared__ int dlt[FPC];
    __shared__ int sc[FPC];
    int c = blockIdx.x / BPC;
    int seg = blockIdx.x % BPC;
    int cs = bstart[c * FPC];
    int ce = bstart[min((c + 1) * FPC, B2)];
    int base = cs + seg * EPB_A;
    int n = ce - base;
    if (n <= 0) return;                              // uniform per block
    if (n > EPB_A) n = EPB_A;
    int tid = threadIdx.x;
    if (tid < FPC) hist[tid] = 0;
    __syncthreads();
    int keys[EPT]; int vls[EPT]; int frk[EPT];       // frk: fine<<13|rank
    #pragma unroll
    for (int k = 0; k < EPT; ++k) {
        int idx = k * TPB_A + tid;
        if (idx < n) {
            int2 e = temp1[base + idx];
            int f = (e.x >> 26) & 31;                // bits 7..11 of row
            keys[k] = e.x; vls[k] = e.y;
            frk[k] = (f << 13) | atomicAdd(&hist[f], 1);
        }
    }
    __syncthreads();
    if (tid < FPC) sc[tid] = hist[tid];
    __syncthreads();
    #pragma unroll
    for (int off = 1; off < FPC; off <<= 1) {
        int u = (tid >= off && tid < FPC) ? sc[tid - off] : 0;
        __syncthreads();
        if (tid < FPC) sc[tid] += u;
        __syncthreads();
    }
    if (tid < FPC) {
        int cnt = hist[tid];
        int ex = sc[tid] - cnt;
        bnd[tid] = ex;
        dlt[tid] = (cnt ? atomicAdd(&bfill[c * FPC + tid], cnt) : 0) - ex;
    }
    if (tid == 0) bnd[FPC] = sc[FPC - 1];
    __syncthreads();
    #pragma unroll
    for (int k = 0; k < EPT; ++k) {
        int idx = k * TPB_A + tid;
        if (idx < n) {
            int p = bnd[frk[k] >> 13] + (frk[k] & 0x1FFF);
            int rl = (keys[k] >> 19) & 127;
            stage[p] = make_int2((rl << 19) | (keys[k] & 0x7FFFF), vls[k]);
        }
    }
    __syncthreads();
    for (int j = tid; j < n; j += TPB_A) {
        int lo = 0, hi = FPC;
        while (hi - lo > 1) { int mid = (lo + hi) >> 1; if (bnd[mid] <= j) lo = mid; else hi = mid; }
        colval[j + dlt[lo]] = stage[j];
    }
}

// ---------------------------------------------------------------------------
// Pass B: exact within-bucket counting sort, IN-PLACE on colval (the <=CAP
// path fully stages the region in LDS between read and write). Produces
// row_start. Fallback (count > CAP, never for uniform data) bounces through
// scratch (the dead temp1 region).
__global__ __launch_bounds__(256) void sort_bucket2(
    const int* __restrict__ bstart, int* __restrict__ row_start,
    int2* __restrict__ colval, int2* __restrict__ scratch) {
    __shared__ int2 stage[CAP];                      // 40 KB
    __shared__ int lstart[RPB2];
    __shared__ int lfill[RPB2];
    int b = blockIdx.x;
    int row0 = b * RPB2;
    int rcount = NN - row0; if (rcount > RPB2) rcount = RPB2;
    int tid = threadIdx.x;
    int s = bstart[b];
    int count = bstart[b + 1] - s;

    if (tid < RPB2) lfill[tid] = 0;
    __syncthreads();

    // pass 1: per-row counts of this bucket's edges
    for (int i = tid; i < count; i += 256) {
        int rl = colval[s + i].x >> 19;
        atomicAdd(&lfill[rl], 1);
    }
    __syncthreads();

    // 128-wide Hillis-Steele scan -> exclusive per-row offsets
    int val = (tid < RPB2) ? lfill[tid] : 0;
    if (tid < RPB2) lstart[tid] = val;
    __syncthreads();
    for (int off = 1; off < RPB2; off <<= 1) {
        int u = (tid >= off && tid < RPB2) ? lstart[tid - off] : 0;
        __syncthreads();
        if (tid < RPB2) lstart[tid] += u;
        __syncthreads();
    }
    int ex = (tid < RPB2) ? lstart[tid] - val : 0;
    if (tid < RPB2) {
        lstart[tid] = ex;
        lfill[tid] = 0;                              // reset for rank pass
        if (tid < rcount) row_start[row0 + tid] = s + ex;
    }
    if (b == 0 && tid == 0) row_start[NN] = NE;
    __syncthreads();

    // pass 2: rank + stage + in-place coalesced write-back
    if (count <= CAP) {
        for (int i = tid; i < count; i += 256) {
            int2 e = colval[s + i];
            int rl = e.x >> 19;
            int pos = lstart[rl] + atomicAdd(&lfill[rl], 1);
            stage[pos] = make_int2(e.x & 0x7FFFF, e.y);
        }
        __syncthreads();
        for (int i = tid; i < count; i += 256) colval[s + i] = stage[i];
    } else {
        for (int i = tid; i < count; i += 256) scratch[s + i] = colval[s + i];
        __syncthreads();
        for (int i = tid; i < count; i += 256) {
            int2 e = scratch[s + i];
            int rl = e.x >> 19;
            int pos = lstart[rl] + atomicAdd(&lfill[rl], 1);
            colval[s + pos] = make_int2(e.x & 0x7FFFF, e.y);
        }
    }
}

// ---------------------------------------------------------------------------
// Atomic-free SpMM, wide-gather layout: ONE wave64 per row (unchanged R4).
template <bool LAST>
__global__ __launch_bounds__(256) void spmm_csr(
    const int* __restrict__ row_start, const int2* __restrict__ colval,
    const __half* __restrict__ xh, __half* __restrict__ yh,
    float* __restrict__ acc) {
    int lane = threadIdx.x & 63;
    int grp = lane >> 3;
    int fq = lane & 7;
    int row = (blockIdx.x * 256 + threadIdx.x) >> 6;
    if (row >= NN) return;
    int s = row_start[row];
    int e = row_start[row + 1];
    if (s == e) {                                    // empty row (paranoia)
        if (lane < 8) {
            size_t idx = (size_t)row * D + lane * 4;
            if (!LAST) *(uint2*)(yh + idx) = make_uint2(0u, 0u);
            float4 av = *(const float4*)(acc + idx);
            if (LAST) { av.x *= 0.25f; av.y *= 0.25f; av.z *= 0.25f; av.w *= 0.25f; }
            *(float4*)(acc + idx) = av;
        }
        return;
    }
    float a0 = 0.f, a1 = 0.f, a2 = 0.f, a3 = 0.f;
    float b0 = 0.f, b1 = 0.f, b2 = 0.f, b3 = 0.f;
    int i = s;
    for (; i + 16 <= e; i += 16) {
        int2 cvA = colval[i + grp];
        int2 cvB = colval[i + 8 + grp];
        uint2 hA = *(const uint2*)(xh + (size_t)cvA.x * D + fq * 4);
        uint2 hB = *(const uint2*)(xh + (size_t)cvB.x * D + fq * 4);
        float vA = __int_as_float(cvA.y);
        float vB = __int_as_float(cvB.y);
        float2 fA0 = __half22float2(*(__half2*)&hA.x);
        float2 fA1 = __half22float2(*(__half2*)&hA.y);
        float2 fB0 = __half22float2(*(__half2*)&hB.x);
        float2 fB1 = __half22float2(*(__half2*)&hB.y);
        a0 += vA * fA0.x; a1 += vA * fA0.y; a2 += vA * fA1.x; a3 += vA * fA1.y;
        b0 += vB * fB0.x; b1 += vB * fB0.y; b2 += vB * fB1.x; b3 += vB * fB1.y;
    }
    if (i < e) {                                     // masked tail, 1..15 edges
        int iA = i + grp;
        int iB = i + 8 + grp;
        int cA = (iA < e) ? iA : (e - 1);            // clamp: stay on hot lines
        int cB = (iB < e) ? iB : (e - 1);
        int2 cvA = colval[cA];
        int2 cvB = colval[cB];
        uint2 hA = *(const uint2*)(xh + (size_t)cvA.x * D + fq * 4);
        uint2 hB = *(const uint2*)(xh + (size_t)cvB.x * D + fq * 4);
        float vA = (iA < e) ? __int_as_float(cvA.y) : 0.f;
        float vB = (iB < e) ? __int_as_float(cvB.y) : 0.f;
        float2 fA0 = __half22float2(*(__half2*)&hA.x);
        float2 fA1 = __half22float2(*(__half2*)&hA.y);
        float2 fB0 = __half22float2(*(__half2*)&hB.x);
        float2 fB1 = __half22float2(*(__half2*)&hB.y);
        a0 += vA * fA0.x; a1 += vA * fA0.y; a2 += vA * fA1.x; a3 += vA * fA1.y;
        b0 += vB * fB0.x; b1 += vB * fB0.y; b2 += vB * fB1.x; b3 += vB * fB1.y;
    }
    a0 += b0; a1 += b1; a2 += b2; a3 += b3;
    #pragma unroll
    for (int m = 8; m <= 32; m <<= 1) {
        a0 += __shfl_xor(a0, m, 64);
        a1 += __shfl_xor(a1, m, 64);
        a2 += __shfl_xor(a2, m, 64);
        a3 += __shfl_xor(a3, m, 64);
    }
    if (lane < 8) {                                  // grp==0, fq==lane
        size_t idx = (size_t)row * D + lane * 4;
        if (!LAST) {
            __half2 h01 = __float22half2_rn(make_float2(a0, a1));
            __half2 h23 = __float22half2_rn(make_float2(a2, a3));
            *(uint2*)(yh + idx) =
                make_uint2(*(uint32_t*)&h01, *(uint32_t*)&h23);
        }
        float4 av = *(const float4*)(acc + idx);
        av.x += a0; av.y += a1; av.z += a2; av.w += a3;
        if (LAST) { av.x *= 0.25f; av.y *= 0.25f; av.z *= 0.25f; av.w *= 0.25f; }
        *(float4*)(acc + idx) = av;
    }
}

extern "C" void kernel_launch(void* const* d_in, const int* in_sizes, int n_in,
                              void* d_out, int out_size, void* d_ws, size_t ws_size,
                              hipStream_t stream) {
    const int*   rows   = (const int*)d_in[0];
    const int*   cols   = (const int*)d_in[1];
    const float* vals   = (const float*)d_in[2];
    const float* user_w = (const float*)d_in[3];
    const float* item_w = (const float*)d_in[4];

    float* acc = (float*)d_out;                      // fp32 output/accumulator

    // ws layout (16B alignment maintained):
    //   [0, 76.8MB): temp1 (A1 out; also sort fallback scratch);
    //                post-build xh (19.2MB) | yh (19.2MB) alias its front
    //   colval (76.8MB) | bcounts[B2] | bstart[B2+1] | bfill[B2] | cfill[NC]
    //   | row_start[NN+1]
    __half* xh = (__half*)d_ws;
    __half* yh = xh + (size_t)TOTAL;
    int2*  temp1 = (int2*)d_ws;
    int2*  colval = (int2*)((char*)d_ws + 2ull * (size_t)TOTAL * sizeof(float));
    int*   bcounts = (int*)(colval + (size_t)NE);
    int*   bstart = bcounts + B2;                    // B2+1 entries
    int*   bfill = bstart + (B2 + 1);
    int*   cfill = bfill + B2;                       // NC entries
    int*   row_start = cfill + NC;                   // NN+1 entries

    const int vec_blocks   = (TOTAL / 4 + 255) / 256;   // 9375
    const int partA_blocks = (NE + EPB_A - 1) / EPB_A;  // 586
    const int partF_blocks = NC * BPC;                  // 666
    const int row_blocks   = (NN + 3) / 4;              // 75000 (1 wave64/row)

    // Build exact CSR: hist -> scan -> coarse partition -> fine partition ->
    // in-place per-bucket row sort
    hipMemsetAsync(bcounts, 0, (size_t)B2 * sizeof(int), stream);
    bucket_hist<<<NB_H, TPB_H, 0, stream>>>((const int4*)rows, bcounts);
    scan_buckets<<<1, 1024, 0, stream>>>(bcounts, bstart, bfill, cfill);
    partition_coarse<<<partA_blocks, TPB_A, 0, stream>>>(
        (const int4*)rows, (const int4*)cols, (const float4*)vals, cfill, temp1);
    partition_fine<<<partF_blocks, TPB_A, 0, stream>>>(
        (const int2*)temp1, bstart, bfill, colval);
    sort_bucket2<<<B2, 256, 0, stream>>>(bstart, row_start, colval, temp1);

    // Embeddings + accumulator (after build: temp1 aliases xh|yh)
    init_x_acc<<<vec_blocks, 256, 0, stream>>>(
        (const float4*)user_w, (const float4*)item_w, (ushort4*)xh, (float4*)acc);

    // 3 propagation layers, atomic-free, wide fp16 gather
    spmm_csr<false><<<row_blocks, 256, 0, stream>>>(row_start, colval, xh, yh, acc);
    spmm_csr<false><<<row_blocks, 256, 0, stream>>>(row_start, colval, yh, xh, acc);
    spmm_csr<true ><<<row_blocks, 256, 0, stream>>>(row_start, colval, xh, yh, acc);
}

// Round 6
// 808.354 us; speedup vs baseline: 1.6386x; 1.0221x over previous
//
#include <hip/hip_runtime.h>
#include <hip/hip_fp16.h>
#include <stdint.h>

#define NUM_USERS 200000
#define NUM_ITEMS 100000
#define NN (NUM_USERS + NUM_ITEMS)   // 300000
#define D 32
#define NE 9600000
#define TOTAL (NN * D)               // 9,600,000 elements

#define RPB2 128                     // rows per fine bucket
#define B2 ((NN + RPB2 - 1) / RPB2)  // 2344 fine buckets
#define CAP 5120                     // LDS stage capacity in sort (mean 4096, sigma ~64)

#define CSH 12                       // coarse bucket = row >> 12 (4096 rows)
#define NC ((NN + (1 << CSH) - 1) >> CSH)   // 74 coarse buckets
#define FPC 32                       // fine buckets per coarse (4096/128)
#define BPC 9                        // fine-pass blocks per coarse region

#define TPB_A 1024                   // partition block size
#define EPT 16                       // edges per thread in partition
#define EPB_A (TPB_A * EPT)          // 16384 edges per block

#define TPB_H 1024                   // bucket-hist block size
#define EPT_H 32
#define EPB_H (TPB_H * EPT_H)        // 32768 edges per block
#define NB_H ((NE + EPB_H - 1) / EPB_H)  // 293 blocks

// ---------------------------------------------------------------------------
// init: x0h = fp16 copy of concat(user_w, item_w). acc is NOT touched —
// the mean is computed in one final pass over x0h..x3h (saves the per-layer
// acc read+write round-trip, 230MB of past-L2 traffic across 3 layers).
__global__ __launch_bounds__(256) void init_x0(
    const float4* __restrict__ user_w, const float4* __restrict__ item_w,
    ushort4* __restrict__ x0h) {
    int i = blockIdx.x * 256 + threadIdx.x;
    const int total4 = TOTAL / 4;
    const int ub4 = (NUM_USERS * D) / 4;
    if (i < total4) {
        float4 v = (i < ub4) ? user_w[i] : item_w[i - ub4];
        ushort4 h;
        h.x = __half_as_ushort(__float2half(v.x));
        h.y = __half_as_ushort(__float2half(v.y));
        h.z = __half_as_ushort(__float2half(v.z));
        h.w = __half_as_ushort(__float2half(v.w));
        x0h[i] = h;
    }
}

// ---------------------------------------------------------------------------
// Fine-bucket degree histogram, LDS-privatized.
__global__ __launch_bounds__(TPB_H) void bucket_hist(
    const int4* __restrict__ rows4, int* __restrict__ bcounts) {
    __shared__ int hist[B2];                         // 9376 B
    int tid = threadIdx.x;
    for (int i = tid; i < B2; i += TPB_H) hist[i] = 0;
    __syncthreads();
    int base4 = blockIdx.x * (EPB_H / 4);
    #pragma unroll
    for (int k = 0; k < EPT_H / 4; ++k) {
        int i4 = base4 + k * TPB_H + tid;
        if (i4 < NE / 4) {
            int4 r = rows4[i4];
            atomicAdd(&hist[r.x >> 7], 1);
            atomicAdd(&hist[r.y >> 7], 1);
            atomicAdd(&hist[r.z >> 7], 1);
            atomicAdd(&hist[r.w >> 7], 1);
        }
    }
    __syncthreads();
    for (int b = tid; b < B2; b += TPB_H) {
        int c = hist[b];
        if (c) atomicAdd(&bcounts[b], c);
    }
}

// ---------------------------------------------------------------------------
// Single-block exclusive scan of the 2344 fine counts -> bstart, bfill, cfill.
__global__ __launch_bounds__(1024) void scan_buckets(
    const int* __restrict__ bcounts, int* __restrict__ bstart,
    int* __restrict__ bfill, int* __restrict__ cfill) {
    __shared__ int lds[1024];
    int t = threadIdx.x;
    int v[4];
    int s = 0;
    #pragma unroll
    for (int k = 0; k < 4; ++k) {
        int b = t * 4 + k;
        v[k] = (b < B2) ? bcounts[b] : 0;
        s += v[k];
    }
    lds[t] = s;
    __syncthreads();
    for (int off = 1; off < 1024; off <<= 1) {
        int u = (t >= off) ? lds[t - off] : 0;
        __syncthreads();
        lds[t] += u;
        __syncthreads();
    }
    int ex = lds[t] - s;                             // exclusive prefix of chunk
    #pragma unroll
    for (int k = 0; k < 4; ++k) {
        int b = t * 4 + k;
        if (b < B2) {
            bstart[b] = ex;
            bfill[b] = ex;
            if ((b & (FPC - 1)) == 0) cfill[b >> 5] = ex;
        }
        ex += v[k];
    }
    if (t == 1023) bstart[B2] = ex;                  // == NE
}

// ---------------------------------------------------------------------------
// Pass A1: coarse partition (74 buckets of 4096 rows), LDS-staged,
// position-major coalesced flush (runs avg 221 edges = 1.77KB).
__global__ __launch_bounds__(TPB_A) void partition_coarse(
    const int4* __restrict__ rows4, const int4* __restrict__ cols4,
    const float4* __restrict__ vals4, int* __restrict__ cfill,
    int2* __restrict__ temp1) {
    __shared__ int2 stage[EPB_A];                    // 128 KB
    __shared__ int hist[NC];
    __shared__ int bnd[NC + 1];
    __shared__ int dlt[NC];
    __shared__ int sc[128];
    int tid = threadIdx.x;
    if (tid < NC) hist[tid] = 0;
    __syncthreads();

    int base4 = blockIdx.x * (EPB_A / 4);
    int keys[EPT]; int vls[EPT]; int crk[EPT];       // crk: coarse<<13|rank

    #pragma unroll
    for (int k = 0; k < EPT / 4; ++k) {
        int i4 = base4 + k * TPB_A + tid;
        if (i4 < NE / 4) {
            int4 r = rows4[i4];
            int4 c = cols4[i4];
            float4 v = vals4[i4];
            int c0 = r.x >> CSH, c1 = r.y >> CSH, c2 = r.z >> CSH, c3 = r.w >> CSH;
            keys[k*4+0] = ((r.x & 4095) << 19) | c.x; vls[k*4+0] = __float_as_int(v.x);
            crk[k*4+0] = (c0 << 13) | atomicAdd(&hist[c0], 1);
            keys[k*4+1] = ((r.y & 4095) << 19) | c.y; vls[k*4+1] = __float_as_int(v.y);
            crk[k*4+1] = (c1 << 13) | atomicAdd(&hist[c1], 1);
            keys[k*4+2] = ((r.z & 4095) << 19) | c.z; vls[k*4+2] = __float_as_int(v.z);
            crk[k*4+2] = (c2 << 13) | atomicAdd(&hist[c2], 1);
            keys[k*4+3] = ((r.w & 4095) << 19) | c.w; vls[k*4+3] = __float_as_int(v.w);
            crk[k*4+3] = (c3 << 13) | atomicAdd(&hist[c3], 1);
        }
    }
    __syncthreads();
    if (tid < 128) sc[tid] = (tid < NC) ? hist[tid] : 0;
    __syncthreads();
    #pragma unroll
    for (int off = 1; off < 128; off <<= 1) {
        int u = (tid >= off && tid < 128) ? sc[tid - off] : 0;
        __syncthreads();
        if (tid < 128) sc[tid] += u;
        __syncthreads();
    }
    if (tid < NC) {
        int cnt = hist[tid];
        int ex = sc[tid] - cnt;
        bnd[tid] = ex;
        dlt[tid] = (cnt ? atomicAdd(&cfill[tid], cnt) : 0) - ex;
    }
    if (tid == 0) bnd[NC] = sc[NC - 1];
    __syncthreads();
    #pragma unroll
    for (int k = 0; k < EPT / 4; ++k) {
        int i4 = base4 + k * TPB_A + tid;
        if (i4 < NE / 4) {
            #pragma unroll
            for (int j = 0; j < 4; ++j) {
                int e = k * 4 + j;
                int p = bnd[crk[e] >> 13] + (crk[e] & 0x1FFF);
                stage[p] = make_int2(keys[e], vls[e]);
            }
        }
    }
    __syncthreads();
    int ntot = bnd[NC];
    for (int j = tid; j < ntot; j += TPB_A) {
        int lo = 0, hi = NC;
        while (hi - lo > 1) { int mid = (lo + hi) >> 1; if (bnd[mid] <= j) lo = mid; else hi = mid; }
        temp1[j + dlt[lo]] = stage[j];
    }
}

// ---------------------------------------------------------------------------
// Pass A2: fine partition within each coarse region (32 fine buckets).
__global__ __launch_bounds__(TPB_A) void partition_fine(
    const int2* __restrict__ temp1, const int* __restrict__ bstart,
    int* __restrict__ bfill, int2* __restrict__ colval) {
    __shared__ int2 stage[EPB_A];                    // 128 KB
    __shared__ int hist[FPC];
    __shared__ int bnd[FPC + 1];
    __shared__ int dlt[FPC];
    __shared__ int sc[FPC];
    int c = blockIdx.x / BPC;
    int seg = blockIdx.x % BPC;
    int cs = bstart[c * FPC];
    int ce = bstart[min((c + 1) * FPC, B2)];
    int base = cs + seg * EPB_A;
    int n = ce - base;
    if (n <= 0) return;                              // uniform per block
    if (n > EPB_A) n = EPB_A;
    int tid = threadIdx.x;
    if (tid < FPC) hist[tid] = 0;
    __syncthreads();
    int keys[EPT]; int vls[EPT]; int frk[EPT];       // frk: fine<<13|rank
    #pragma unroll
    for (int k = 0; k < EPT; ++k) {
        int idx = k * TPB_A + tid;
        if (idx < n) {
            int2 e = temp1[base + idx];
            int f = (e.x >> 26) & 31;                // bits 7..11 of row
            keys[k] = e.x; vls[k] = e.y;
            frk[k] = (f << 13) | atomicAdd(&hist[f], 1);
        }
    }
    __syncthreads();
    if (tid < FPC) sc[tid] = hist[tid];
    __syncthreads();
    #pragma unroll
    for (int off = 1; off < FPC; off <<= 1) {
        int u = (tid >= off && tid < FPC) ? sc[tid - off] : 0;
        __syncthreads();
        if (tid < FPC) sc[tid] += u;
        __syncthreads();
    }
    if (tid < FPC) {
        int cnt = hist[tid];
        int ex = sc[tid] - cnt;
        bnd[tid] = ex;
        dlt[tid] = (cnt ? atomicAdd(&bfill[c * FPC + tid], cnt) : 0) - ex;
    }
    if (tid == 0) bnd[FPC] = sc[FPC - 1];
    __syncthreads();
    #pragma unroll
    for (int k = 0; k < EPT; ++k) {
        int idx = k * TPB_A + tid;
        if (idx < n) {
            int p = bnd[frk[k] >> 13] + (frk[k] & 0x1FFF);
            int rl = (keys[k] >> 19) & 127;
            stage[p] = make_int2((rl << 19) | (keys[k] & 0x7FFFF), vls[k]);
        }
    }
    __syncthreads();
    for (int j = tid; j < n; j += TPB_A) {
        int lo = 0, hi = FPC;
        while (hi - lo > 1) { int mid = (lo + hi) >> 1; if (bnd[mid] <= j) lo = mid; else hi = mid; }
        colval[j + dlt[lo]] = stage[j];
    }
}

// ---------------------------------------------------------------------------
// Pass B: exact within-bucket counting sort, in-place on colval; row_start out.
__global__ __launch_bounds__(256) void sort_bucket2(
    const int* __restrict__ bstart, int* __restrict__ row_start,
    int2* __restrict__ colval, int2* __restrict__ scratch) {
    __shared__ int2 stage[CAP];                      // 40 KB
    __shared__ int lstart[RPB2];
    __shared__ int lfill[RPB2];
    int b = blockIdx.x;
    int row0 = b * RPB2;
    int rcount = NN - row0; if (rcount > RPB2) rcount = RPB2;
    int tid = threadIdx.x;
    int s = bstart[b];
    int count = bstart[b + 1] - s;

    if (tid < RPB2) lfill[tid] = 0;
    __syncthreads();

    for (int i = tid; i < count; i += 256) {
        int rl = colval[s + i].x >> 19;
        atomicAdd(&lfill[rl], 1);
    }
    __syncthreads();

    int val = (tid < RPB2) ? lfill[tid] : 0;
    if (tid < RPB2) lstart[tid] = val;
    __syncthreads();
    for (int off = 1; off < RPB2; off <<= 1) {
        int u = (tid >= off && tid < RPB2) ? lstart[tid - off] : 0;
        __syncthreads();
        if (tid < RPB2) lstart[tid] += u;
        __syncthreads();
    }
    int ex = (tid < RPB2) ? lstart[tid] - val : 0;
    if (tid < RPB2) {
        lstart[tid] = ex;
        lfill[tid] = 0;                              // reset for rank pass
        if (tid < rcount) row_start[row0 + tid] = s + ex;
    }
    if (b == 0 && tid == 0) row_start[NN] = NE;
    __syncthreads();

    if (count <= CAP) {
        for (int i = tid; i < count; i += 256) {
            int2 e = colval[s + i];
            int rl = e.x >> 19;
            int pos = lstart[rl] + atomicAdd(&lfill[rl], 1);
            stage[pos] = make_int2(e.x & 0x7FFFF, e.y);
        }
        __syncthreads();
        for (int i = tid; i < count; i += 256) colval[s + i] = stage[i];
    } else {
        for (int i = tid; i < count; i += 256) scratch[s + i] = colval[s + i];
        __syncthreads();
        for (int i = tid; i < count; i += 256) {
            int2 e = scratch[s + i];
            int rl = e.x >> 19;
            int pos = lstart[rl] + atomicAdd(&lfill[rl], 1);
            colval[s + pos] = make_int2(e.x & 0x7FFFF, e.y);
        }
    }
}

__device__ __forceinline__ float2 h2f(uint32_t u) {
    return __half22float2(*(__half2*)&u);
}

// ---------------------------------------------------------------------------
// Atomic-free SpMM, wide-gather: ONE wave64 per row, 32-edge step with FOUR
// independent colval->gather chains (max MLP; avg degree = 32 so a typical
// row is one full step + one masked step). colval is read NON-TEMPORALLY so
// its 77MB stream doesn't evict xh from L2 (xh L2 hits are the only thing
// that reduces the 614MB gather line traffic). No acc fusion — y only.
__global__ __launch_bounds__(256) void spmm_csr(
    const int* __restrict__ row_start, const int2* __restrict__ colval,
    const __half* __restrict__ xh, __half* __restrict__ yh) {
    int lane = threadIdx.x & 63;
    int grp = lane >> 3;
    int fq = lane & 7;
    int row = (blockIdx.x * 256 + threadIdx.x) >> 6;
    if (row >= NN) return;
    int s = row_start[row];
    int e = row_start[row + 1];
    const int64_t* cv8 = (const int64_t*)colval;
    float a0 = 0.f, a1 = 0.f, a2 = 0.f, a3 = 0.f;
    int i = s;
    for (; i + 32 <= e; i += 32) {                   // full step: 4 chains
        int64_t p0 = __builtin_nontemporal_load(&cv8[i + grp]);
        int64_t p1 = __builtin_nontemporal_load(&cv8[i + 8 + grp]);
        int64_t p2 = __builtin_nontemporal_load(&cv8[i + 16 + grp]);
        int64_t p3 = __builtin_nontemporal_load(&cv8[i + 24 + grp]);
        uint2 h0 = *(const uint2*)(xh + (size_t)(uint32_t)p0 * D + fq * 4);
        uint2 h1 = *(const uint2*)(xh + (size_t)(uint32_t)p1 * D + fq * 4);
        uint2 h2 = *(const uint2*)(xh + (size_t)(uint32_t)p2 * D + fq * 4);
        uint2 h3 = *(const uint2*)(xh + (size_t)(uint32_t)p3 * D + fq * 4);
        float v0 = __int_as_float((int)(p0 >> 32));
        float v1 = __int_as_float((int)(p1 >> 32));
        float v2 = __int_as_float((int)(p2 >> 32));
        float v3 = __int_as_float((int)(p3 >> 32));
        float2 f;
        f = h2f(h0.x); a0 += v0 * f.x; a1 += v0 * f.y;
        f = h2f(h0.y); a2 += v0 * f.x; a3 += v0 * f.y;
        f = h2f(h1.x); a0 += v1 * f.x; a1 += v1 * f.y;
        f = h2f(h1.y); a2 += v1 * f.x; a3 += v1 * f.y;
        f = h2f(h2.x); a0 += v2 * f.x; a1 += v2 * f.y;
        f = h2f(h2.y); a2 += v2 * f.x; a3 += v2 * f.y;
        f = h2f(h3.x); a0 += v3 * f.x; a1 += v3 * f.y;
        f = h2f(h3.y); a2 += v3 * f.x; a3 += v3 * f.y;
    }
    if (i < e) {                                     // masked step: clamp+zero
        int last = e - 1;
        int i0 = i + grp,      c0 = (i0 < e) ? i0 : last;
        int i1 = i + 8 + grp,  c1 = (i1 < e) ? i1 : last;
        int i2 = i + 16 + grp, c2 = (i2 < e) ? i2 : last;
        int i3 = i + 24 + grp, c3 = (i3 < e) ? i3 : last;
        int64_t p0 = __builtin_nontemporal_load(&cv8[c0]);
        int64_t p1 = __builtin_nontemporal_load(&cv8[c1]);
        int64_t p2 = __builtin_nontemporal_load(&cv8[c2]);
        int64_t p3 = __builtin_nontemporal_load(&cv8[c3]);
        uint2 h0 = *(const uint2*)(xh + (size_t)(uint32_t)p0 * D + fq * 4);
        uint2 h1 = *(const uint2*)(xh + (size_t)(uint32_t)p1 * D + fq * 4);
        uint2 h2 = *(const uint2*)(xh + (size_t)(uint32_t)p2 * D + fq * 4);
        uint2 h3 = *(const uint2*)(xh + (size_t)(uint32_t)p3 * D + fq * 4);
        float v0 = (i0 < e) ? __int_as_float((int)(p0 >> 32)) : 0.f;
        float v1 = (i1 < e) ? __int_as_float((int)(p1 >> 32)) : 0.f;
        float v2 = (i2 < e) ? __int_as_float((int)(p2 >> 32)) : 0.f;
        float v3 = (i3 < e) ? __int_as_float((int)(p3 >> 32)) : 0.f;
        float2 f;
        f = h2f(h0.x); a0 += v0 * f.x; a1 += v0 * f.y;
        f = h2f(h0.y); a2 += v0 * f.x; a3 += v0 * f.y;
        f = h2f(h1.x); a0 += v1 * f.x; a1 += v1 * f.y;
        f = h2f(h1.y); a2 += v1 * f.x; a3 += v1 * f.y;
        f = h2f(h2.x); a0 += v2 * f.x; a1 += v2 * f.y;
        f = h2f(h2.y); a2 += v2 * f.x; a3 += v2 * f.y;
        f = h2f(h3.x); a0 += v3 * f.x; a1 += v3 * f.y;
        f = h2f(h3.y); a2 += v3 * f.x; a3 += v3 * f.y;
    }
    #pragma unroll
    for (int m = 8; m <= 32; m <<= 1) {              // butterfly over edge slots
        a0 += __shfl_xor(a0, m, 64);
        a1 += __shfl_xor(a1, m, 64);
        a2 += __shfl_xor(a2, m, 64);
        a3 += __shfl_xor(a3, m, 64);
    }
    if (lane < 8) {                                  // grp==0, fq==lane
        size_t idx = (size_t)row * D + lane * 4;
        __half2 h01 = __float22half2_rn(make_float2(a0, a1));
        __half2 h23 = __float22half2_rn(make_float2(a2, a3));
        *(uint2*)(yh + idx) = make_uint2(*(uint32_t*)&h01, *(uint32_t*)&h23);
    }
}

// ---------------------------------------------------------------------------
// Final mean: acc = 0.25 * (x0 + x1 + x2 + x3), fp16-in fp32-out, 16B loads.
__global__ __launch_bounds__(256) void finalize_mean(
    const uint4* __restrict__ x0, const uint4* __restrict__ x1,
    const uint4* __restrict__ x2, const uint4* __restrict__ x3,
    float4* __restrict__ acc) {
    int i = blockIdx.x * 256 + threadIdx.x;
    if (i >= TOTAL / 8) return;
    uint4 a = x0[i], b = x1[i], c = x2[i], d = x3[i];
    float2 s0, s1, s2, s3, t;
    s0 = h2f(a.x); t = h2f(b.x); s0.x += t.x; s0.y += t.y;
    t = h2f(c.x); s0.x += t.x; s0.y += t.y; t = h2f(d.x); s0.x += t.x; s0.y += t.y;
    s1 = h2f(a.y); t = h2f(b.y); s1.x += t.x; s1.y += t.y;
    t = h2f(c.y); s1.x += t.x; s1.y += t.y; t = h2f(d.y); s1.x += t.x; s1.y += t.y;
    s2 = h2f(a.z); t = h2f(b.z); s2.x += t.x; s2.y += t.y;
    t = h2f(c.z); s2.x += t.x; s2.y += t.y; t = h2f(d.z); s2.x += t.x; s2.y += t.y;
    s3 = h2f(a.w); t = h2f(b.w); s3.x += t.x; s3.y += t.y;
    t = h2f(c.w); s3.x += t.x; s3.y += t.y; t = h2f(d.w); s3.x += t.x; s3.y += t.y;
    acc[2 * i]     = make_float4(s0.x * 0.25f, s0.y * 0.25f, s1.x * 0.25f, s1.y * 0.25f);
    acc[2 * i + 1] = make_float4(s2.x * 0.25f, s2.y * 0.25f, s3.x * 0.25f, s3.y * 0.25f);
}

extern "C" void kernel_launch(void* const* d_in, const int* in_sizes, int n_in,
                              void* d_out, int out_size, void* d_ws, size_t ws_size,
                              hipStream_t stream) {
    const int*   rows   = (const int*)d_in[0];
    const int*   cols   = (const int*)d_in[1];
    const float* vals   = (const float*)d_in[2];
    const float* user_w = (const float*)d_in[3];
    const float* item_w = (const float*)d_in[4];

    float* acc = (float*)d_out;                      // fp32 output

    // ws layout (16B alignment maintained):
    //   [0, 76.8MB): temp1 (A1 out; sort fallback scratch);
    //                post-build x0h|x1h|x2h|x3h (4 x 19.2MB) alias it
    //   colval (76.8MB) | bcounts[B2] | bstart[B2+1] | bfill[B2] | cfill[NC]
    //   | row_start[NN+1]
    __half* x0h = (__half*)d_ws;
    __half* x1h = x0h + (size_t)TOTAL;
    __half* x2h = x1h + (size_t)TOTAL;
    __half* x3h = x2h + (size_t)TOTAL;
    int2*  temp1 = (int2*)d_ws;
    int2*  colval = (int2*)((char*)d_ws + 2ull * (size_t)TOTAL * sizeof(float));
    int*   bcounts = (int*)(colval + (size_t)NE);
    int*   bstart = bcounts + B2;                    // B2+1 entries
    int*   bfill = bstart + (B2 + 1);
    int*   cfill = bfill + B2;                       // NC entries
    int*   row_start = cfill + NC;                   // NN+1 entries

    const int vec_blocks   = (TOTAL / 4 + 255) / 256;   // 9375
    const int mean_blocks  = (TOTAL / 8 + 255) / 256;   // 4688
    const int partA_blocks = (NE + EPB_A - 1) / EPB_A;  // 586
    const int partF_blocks = NC * BPC;                  // 666
    const int row_blocks   = (NN + 3) / 4;              // 75000 (1 wave64/row)

    // Build exact CSR
    hipMemsetAsync(bcounts, 0, (size_t)B2 * sizeof(int), stream);
    bucket_hist<<<NB_H, TPB_H, 0, stream>>>((const int4*)rows, bcounts);
    scan_buckets<<<1, 1024, 0, stream>>>(bcounts, bstart, bfill, cfill);
    partition_coarse<<<partA_blocks, TPB_A, 0, stream>>>(
        (const int4*)rows, (const int4*)cols, (const float4*)vals, cfill, temp1);
    partition_fine<<<partF_blocks, TPB_A, 0, stream>>>(
        (const int2*)temp1, bstart, bfill, colval);
    sort_bucket2<<<B2, 256, 0, stream>>>(bstart, row_start, colval, temp1);

    // Embeddings (after build: temp1 aliases x0h..x3h)
    init_x0<<<vec_blocks, 256, 0, stream>>>(
        (const float4*)user_w, (const float4*)item_w, (ushort4*)x0h);

    // 3 propagation layers (y only; no acc fusion)
    spmm_csr<<<row_blocks, 256, 0, stream>>>(row_start, colval, x0h, x1h);
    spmm_csr<<<row_blocks, 256, 0, stream>>>(row_start, colval, x1h, x2h);
    spmm_csr<<<row_blocks, 256, 0, stream>>>(row_start, colval, x2h, x3h);

    // acc = mean(x0..x3)
    finalize_mean<<<mean_blocks, 256, 0, stream>>>(
        (const uint4*)x0h, (const uint4*)x1h, (const uint4*)x2h,
        (const uint4*)x3h, (float4*)acc);
}